// Round 3
// baseline (221.466 us; speedup 1.0000x reference)
//
#include <hip/hip_runtime.h>
#include <hip/hip_bf16.h>

// S5 layer, fused MFMA pipeline:
//   k0  : discretization, bf16 operand layouts, lambda power tables
//   g1f : u(fp32)->bf16 reg-staged GEMM -> Bu (packed bf16) + chunk-final states (sfin)
//   s2  : cross-chunk state chain (sfin -> sinv)
//   g2f : per-chunk scan (Bu,sinv -> x in LDS) + output GEMM + D*u -> y

#define P_ 256
#define H_ 256
#define B_ 16
#define L_ 4096
#define LC 64
#define NC (L_/LC)          // 64 chunks per batch
#define SEG 4               // batches per segment
#define NSEG (B_/SEG)
#define MSEG (SEG*L_)       // 16384 rows per segment

typedef __attribute__((ext_vector_type(8))) short short8v;
typedef __attribute__((ext_vector_type(4))) float f32x4;

#define GLOBAL_AS __attribute__((address_space(1)))
#define LDS_AS __attribute__((address_space(3)))

static __device__ __forceinline__ void gl_lds16(const void* g, void* l) {
    __builtin_amdgcn_global_load_lds((const GLOBAL_AS unsigned char*)g,
                                     (LDS_AS unsigned char*)l, 16, 0, 0);
}

static __device__ __forceinline__ unsigned pack_bf16x2(float a, float b) {
    unsigned ua = __float_as_uint(a);
    unsigned ub = __float_as_uint(b);
    ua = (ua + 0x7fffu + ((ua >> 16) & 1u)) >> 16;   // RNE
    ub = (ub + 0x7fffu + ((ub >> 16) & 1u)) >> 16;
    return ua | (ub << 16);
}

static __device__ __forceinline__ unsigned short f2bf(float f) {
    unsigned u = __float_as_uint(f);
    return (unsigned short)((u + 0x7fffu + ((u >> 16) & 1u)) >> 16);
}

// ---------------- k0: discretization + operand layouts + lambda powers -----
// B1op [2P][H] bf16: row 2p = Bbar_re[p][:], row 2p+1 = Bbar_im[p][:]
// C2op [H][2P] bf16: [h][2p] = 2*Cre[h][p], [h][2p+1] = -2*Cim[h][p]
// lamP [P][6] fp32: lam^16, lam^32, lam^48 (re,im each); lamLc = lam^64
__global__ __launch_bounds__(256) void k0_pre(
    const float* __restrict__ Lre, const float* __restrict__ Lim,
    const float* __restrict__ Bre, const float* __restrict__ Bim,
    const float* __restrict__ Cre, const float* __restrict__ Cim,
    const float* __restrict__ lstep,
    float* __restrict__ lam, float* __restrict__ lamLc, float* __restrict__ lamP,
    unsigned short* __restrict__ B1op, unsigned short* __restrict__ C2op)
{
    int bx = blockIdx.x;
    int t  = threadIdx.x;
    {
        int p = bx, h = t;
        float laR = Lre[p], laI = Lim[p];
        float st = expf(lstep[p]);
        float er = expf(laR * st);
        float lr = er * cosf(laI * st);
        float li = er * sinf(laI * st);
        float den = laR * laR + laI * laI;
        float nr = lr - 1.0f, ni = li;
        float cr = (nr * laR + ni * laI) / den;
        float ci = (ni * laR - nr * laI) / den;
        float br = Bre[p * H_ + h], bi = Bim[p * H_ + h];
        B1op[(2 * p) * H_ + h]     = f2bf(cr * br - ci * bi);
        B1op[(2 * p + 1) * H_ + h] = f2bf(cr * bi + ci * br);
        if (t == 0) {
            lam[2 * p] = lr; lam[2 * p + 1] = li;
            float r2 = lr*lr - li*li,  i2 = 2.f*lr*li;       // ^2
            float r4 = r2*r2 - i2*i2,  i4 = 2.f*r2*i2;       // ^4
            float r8 = r4*r4 - i4*i4,  i8 = 2.f*r4*i4;       // ^8
            float r16 = r8*r8 - i8*i8, i16 = 2.f*r8*i8;      // ^16
            float r32 = r16*r16 - i16*i16, i32 = 2.f*r16*i16;// ^32
            float r48 = r32*r16 - i32*i16, i48 = r32*i16 + i32*r16; // ^48
            float r64 = r32*r32 - i32*i32, i64 = 2.f*r32*i32;// ^64
            lamP[6*p+0] = r16; lamP[6*p+1] = i16;
            lamP[6*p+2] = r32; lamP[6*p+3] = i32;
            lamP[6*p+4] = r48; lamP[6*p+5] = i48;
            lamLc[2 * p] = r64; lamLc[2 * p + 1] = i64;
        }
    }
    {
        int h = bx, p = t;
        C2op[(size_t)h * 512 + 2 * p]     = f2bf( 2.0f * Cre[h * P_ + p]);
        C2op[(size_t)h * 512 + 2 * p + 1] = f2bf(-2.0f * Cim[h * P_ + p]);
    }
}

// ---------------- g1f: Bu GEMM (u fp32 in) + chunk-final scan --------------
// A: u [MSEG][256] fp32 (reg-staged -> bf16 LDS); B: B1op [512][256]
// out: Bu [MSEG][256] packed-bf16 dwords; sfin [SEG*NC][256] float2
__global__ __launch_bounds__(256) void g1f_gemm(
    const float* __restrict__ us,
    const unsigned short* __restrict__ B1op,
    const float* __restrict__ lam, const float* __restrict__ lamP,
    unsigned* __restrict__ Bu, float2* __restrict__ sfin)
{
    __shared__ __align__(16) char smem[35328];
    unsigned short* Al = (unsigned short*)smem;            // [128][64] swizzled
    unsigned short* Bl = (unsigned short*)(smem + 16384);  // [128][64] swizzled
    float* epl = (float*)smem;                             // [64][130] epilogue
    float2* fg = (float2*)(smem + 33280);                  // [4][64] scan partials

    int tid = threadIdx.x, w = tid >> 6, lane = tid & 63;
    int wr = w >> 1, wc = w & 1;
    int m0 = blockIdx.x * 128;
    int n0 = blockIdx.y * 128;
    int lr_ = lane & 15, lk = lane >> 4;

    f32x4 acc[4][4];
    #pragma unroll
    for (int m = 0; m < 4; ++m)
        #pragma unroll
        for (int n = 0; n < 4; ++n)
            acc[m][n] = (f32x4){0.f, 0.f, 0.f, 0.f};

    int sw8 = ((lane & 7) ^ ((lane >> 3) & 7)) * 8;   // pre-swizzled src k-offset (B)
    int ar = tid >> 1, akh = (tid & 1) * 32;          // A-stage: row, k-half
    int ar7 = ar & 7;

    for (int kt = 0; kt < 4; ++kt) {
        int k0 = kt * 64;
        // B: global_load_lds, pre-swizzled source
        #pragma unroll
        for (int i = 0; i < 4; ++i) {
            int blk = i * 4 + w;
            int r = blk * 8 + (lane >> 3);
            gl_lds16(B1op + (size_t)(n0 + r) * 256 + k0 + sw8, Bl + blk * 512);
        }
        // A: reg-staged fp32 -> bf16, swizzled ds_write
        {
            const float4* up = (const float4*)(us + (size_t)(m0 + ar) * 256 + k0 + akh);
            unsigned short* arow = Al + ar * 64;
            #pragma unroll
            for (int g = 0; g < 4; ++g) {
                float4 v0 = up[g * 2], v1 = up[g * 2 + 1];
                uint4 o;
                o.x = pack_bf16x2(v0.x, v0.y); o.y = pack_bf16x2(v0.z, v0.w);
                o.z = pack_bf16x2(v1.x, v1.y); o.w = pack_bf16x2(v1.z, v1.w);
                int gg = (tid & 1) * 4 + g;
                *(uint4*)(arow + ((gg ^ ar7) * 8)) = o;
            }
        }
        __syncthreads();
        #pragma unroll
        for (int kk = 0; kk < 2; ++kk) {
            short8v a_[4], b_[4];
            #pragma unroll
            for (int m = 0; m < 4; ++m) {
                int row = wr * 64 + m * 16 + lr_;
                a_[m] = *(const short8v*)&Al[row * 64 + (((lk + 4 * kk) ^ (lr_ & 7)) * 8)];
            }
            #pragma unroll
            for (int n = 0; n < 4; ++n) {
                int row = wc * 64 + n * 16 + lr_;
                b_[n] = *(const short8v*)&Bl[row * 64 + (((lk + 4 * kk) ^ (lr_ & 7)) * 8)];
            }
            #pragma unroll
            for (int m = 0; m < 4; ++m)
                #pragma unroll
                for (int n = 0; n < 4; ++n)
                    acc[m][n] = __builtin_amdgcn_mfma_f32_16x16x32_bf16(a_[m], b_[n], acc[m][n], 0, 0, 0);
        }
        __syncthreads();
    }

    // epilogue: 2 phases of 64 rows (= 1 chunk each)
    int n0d = blockIdx.y * 64;            // Bu dword col base
    int bl = m0 >> 12;                    // batch within segment
    int cl = (m0 & (L_ - 1)) >> 6;        // chunk within batch (base)
    int q = lane;                         // 0..63 (p-pair within tile)
    int g = w;                            // scan group 0..3
    int p_glob = n0d + q;
    float lamr = lam[2 * p_glob], lami = lam[2 * p_glob + 1];

    #pragma unroll
    for (int ph = 0; ph < 2; ++ph) {
        if (wr == ph) {
            #pragma unroll
            for (int m = 0; m < 4; ++m)
                #pragma unroll
                for (int n = 0; n < 4; ++n)
                    #pragma unroll
                    for (int i = 0; i < 4; ++i) {
                        int r = m * 16 + lk * 4 + i;          // 0..63
                        int c = wc * 64 + n * 16 + lr_;       // 0..127
                        epl[r * 130 + c] = acc[m][n][i];
                    }
        }
        __syncthreads();
        // Bu write (packed bf16)
        #pragma unroll
        for (int it = 0; it < 16; ++it) {
            int r = it * 4 + w;
            float2 v = *(const float2*)&epl[r * 130 + 2 * lane];
            Bu[(size_t)(m0 + ph * 64 + r) * 256 + n0d + lane] = pack_bf16x2(v.x, v.y);
        }
        // chunk-final scan, part 1: 4 groups x 16 rows from zero
        {
            float fr = 0.f, fi = 0.f;
            const float* col = epl + 2 * q;
            #pragma unroll
            for (int r = g * 16; r < g * 16 + 16; ++r) {
                float2 bv = *(const float2*)&col[r * 130];
                float nr = lamr * fr - lami * fi + bv.x;
                float ni = lamr * fi + lami * fr + bv.y;
                fr = nr; fi = ni;
            }
            fg[g * 64 + q] = make_float2(fr, fi);
        }
        __syncthreads();
        // part 2: combine  final = lam48*f0 + lam32*f1 + lam16*f2 + f3
        if (g == 0) {
            float2 f0 = fg[q], f1 = fg[64 + q], f2 = fg[128 + q], f3 = fg[192 + q];
            const float* lp = lamP + 6 * p_glob;
            float rr = f3.x + lp[4] * f0.x - lp[5] * f0.y
                            + lp[2] * f1.x - lp[3] * f1.y
                            + lp[0] * f2.x - lp[1] * f2.y;
            float ri = f3.y + lp[4] * f0.y + lp[5] * f0.x
                            + lp[2] * f1.y + lp[3] * f1.x
                            + lp[0] * f2.y + lp[1] * f2.x;
            sfin[(bl * NC + cl + ph) * P_ + p_glob] = make_float2(rr, ri);
        }
        __syncthreads();
    }
}

// ---------------- s2: cross-chunk chain ----------------
__global__ __launch_bounds__(256) void s2_chain(
    const float* __restrict__ lamLc, const float2* __restrict__ sfin,
    float2* __restrict__ sinv)
{
    int bl = blockIdx.x;
    int p = threadIdx.x;
    float ar = lamLc[2 * p], ai = lamLc[2 * p + 1];
    float sr = 0.f, si = 0.f;
    #pragma unroll 8
    for (int c = 0; c < NC; ++c) {
        sinv[(bl * NC + c) * P_ + p] = make_float2(sr, si);
        float2 f = sfin[(bl * NC + c) * P_ + p];
        float nr = ar * sr - ai * si + f.x;
        float ni = ar * si + ai * sr + f.y;
        sr = nr; si = ni;
    }
}

// ---------------- g2f: per-chunk scan + output GEMM + D*u ------------------
// block = 1 chunk (64 l-rows) x full H=256. K=512.
__global__ __launch_bounds__(256) void g2f_gemm(
    const unsigned* __restrict__ Bu,
    const unsigned short* __restrict__ C2op,
    const float* __restrict__ lam, const float2* __restrict__ sinv,
    const float* __restrict__ useg, const float* __restrict__ Dv,
    float* __restrict__ yseg)
{
    __shared__ __align__(16) char xs[64 * 1024];   // 64 rows x 512 bf16, swizzled
    int tid = threadIdx.x, w = tid >> 6, lane = tid & 63;
    int c = blockIdx.x & (NC - 1), bl = blockIdx.x >> 6;

    // phase 1: scan this chunk, write x (bf16) to swizzled LDS
    {
        int p = tid;
        float lr = lam[2 * p], li = lam[2 * p + 1];
        float2 s0 = sinv[(bl * NC + c) * P_ + p];
        float xr = s0.x, xi = s0.y;
        const unsigned* bp = Bu + ((size_t)(bl * L_ + c * LC)) * 256 + p;
        int T = p >> 5, qd = (p & 31) >> 2, pos = p & 3;
        char* base = xs + T * 8192 + (pos << 2);
        #pragma unroll 8
        for (int j = 0; j < LC; ++j) {
            unsigned wv = bp[(size_t)j * 256];
            float ur = __uint_as_float(wv << 16);
            float ui = __uint_as_float(wv & 0xffff0000u);
            float nr = lr * xr - li * xi + ur;
            float ni = lr * xi + li * xr + ui;
            xr = nr; xi = ni;
            *(unsigned*)(base + j * 128 + ((qd ^ (j & 7)) << 4)) = pack_bf16x2(xr, xi);
        }
    }
    __syncthreads();

    // phase 2: GEMM  y[64][256] = x[64][512] * C2op^T[512][256]
    int lr_ = lane & 15, lk = lane >> 4;
    int r7 = lr_ & 7;
    int h0 = w * 64;
    f32x4 acc[4][4];
    #pragma unroll
    for (int m = 0; m < 4; ++m)
        #pragma unroll
        for (int n = 0; n < 4; ++n)
            acc[m][n] = (f32x4){0.f, 0.f, 0.f, 0.f};

    for (int kt = 0; kt < 16; ++kt) {
        int T = kt >> 1, q2 = (kt & 1) * 4 + lk;
        short8v a_[4], b_[4];
        #pragma unroll
        for (int m = 0; m < 4; ++m) {
            int row = m * 16 + lr_;
            a_[m] = *(const short8v*)(xs + T * 8192 + row * 128 + ((q2 ^ r7) << 4));
        }
        #pragma unroll
        for (int n = 0; n < 4; ++n)
            b_[n] = *(const short8v*)&C2op[(size_t)(h0 + n * 16 + lr_) * 512 + kt * 32 + lk * 8];
        #pragma unroll
        for (int m = 0; m < 4; ++m)
            #pragma unroll
            for (int n = 0; n < 4; ++n)
                acc[m][n] = __builtin_amdgcn_mfma_f32_16x16x32_bf16(a_[m], b_[n], acc[m][n], 0, 0, 0);
    }

    float d_[4];
    #pragma unroll
    for (int n = 0; n < 4; ++n) d_[n] = Dv[h0 + n * 16 + lr_];
    #pragma unroll
    for (int m = 0; m < 4; ++m)
        #pragma unroll
        for (int n = 0; n < 4; ++n)
            #pragma unroll
            for (int i = 0; i < 4; ++i) {
                int rl = m * 16 + lk * 4 + i;
                int col = h0 + n * 16 + lr_;
                size_t off = ((size_t)(bl * L_ + c * LC + rl)) * 256 + col;
                yseg[off] = acc[m][n][i] + d_[n] * useg[off];
            }
}

// ---------------- launch ----------------
extern "C" void kernel_launch(void* const* d_in, const int* in_sizes, int n_in,
                              void* d_out, int out_size, void* d_ws, size_t ws_size,
                              hipStream_t stream) {
    (void)in_sizes; (void)n_in; (void)out_size; (void)ws_size;
    const float* u    = (const float*)d_in[0];
    const float* Lre  = (const float*)d_in[1];
    const float* Lim  = (const float*)d_in[2];
    const float* Bre  = (const float*)d_in[3];
    const float* Bim  = (const float*)d_in[4];
    const float* Cre  = (const float*)d_in[5];
    const float* Cim  = (const float*)d_in[6];
    const float* Dv   = (const float*)d_in[7];
    const float* lstep= (const float*)d_in[8];

    char* w0 = (char*)d_ws;
    float* lam   = (float*)w0;  w0 += 2048;
    float* lamLc = (float*)w0;  w0 += 2048;
    float* lamP  = (float*)w0;  w0 += 6 * P_ * 4;
    unsigned short* B1op = (unsigned short*)w0; w0 += 512 * 256 * 2;
    unsigned short* C2op = (unsigned short*)w0; w0 += 256 * 512 * 2;
    float2* sfin = (float2*)w0; w0 += (size_t)SEG * NC * P_ * 8;
    float2* sinv = (float2*)w0; w0 += (size_t)SEG * NC * P_ * 8;
    unsigned* Bu = (unsigned*)w0; w0 += (size_t)MSEG * 256 * 4;

    k0_pre<<<256, 256, 0, stream>>>(Lre, Lim, Bre, Bim, Cre, Cim, lstep,
                                    lam, lamLc, lamP, B1op, C2op);
    for (int s = 0; s < NSEG; ++s) {
        const float* us = u + (size_t)s * MSEG * H_;
        float* ys = (float*)d_out + (size_t)s * MSEG * H_;
        g1f_gemm<<<dim3(MSEG / 128, 4), 256, 0, stream>>>(us, B1op, lam, lamP, Bu, sfin);
        s2_chain<<<SEG, 256, 0, stream>>>(lamLc, sfin, sinv);
        g2f_gemm<<<SEG * NC, 256, 0, stream>>>(Bu, C2op, lam, sinv, us, Dv, ys);
    }
}

// Round 4
// 195.528 us; speedup vs baseline: 1.1327x; 1.1327x over previous
//
#include <hip/hip_runtime.h>
#include <hip/hip_bf16.h>

// S5 layer, fused MFMA pipeline:
//   k0  : discretization, bf16 operand layouts, lambda power tables
//   g1f : u(fp32)->bf16 reg-staged GEMM -> Bu (packed bf16) + chunk-final states (sfin)
//   s2  : cross-chunk state chain (sfin -> sinv)
//   g2h : per-chunk scan (Bu,sinv -> x in LDS) + output GEMM + D*u -> y, h-split x2

#define P_ 256
#define H_ 256
#define B_ 16
#define L_ 4096
#define LC 64
#define NC (L_/LC)          // 64 chunks per batch
#define SEG 4               // batches per segment
#define NSEG (B_/SEG)
#define MSEG (SEG*L_)       // 16384 rows per segment

typedef __attribute__((ext_vector_type(8))) short short8v;
typedef __attribute__((ext_vector_type(4))) float f32x4;

#define GLOBAL_AS __attribute__((address_space(1)))
#define LDS_AS __attribute__((address_space(3)))

static __device__ __forceinline__ void gl_lds16(const void* g, void* l) {
    __builtin_amdgcn_global_load_lds((const GLOBAL_AS unsigned char*)g,
                                     (LDS_AS unsigned char*)l, 16, 0, 0);
}

static __device__ __forceinline__ unsigned pack_bf16x2(float a, float b) {
    unsigned ua = __float_as_uint(a);
    unsigned ub = __float_as_uint(b);
    ua = (ua + 0x7fffu + ((ua >> 16) & 1u)) >> 16;   // RNE
    ub = (ub + 0x7fffu + ((ub >> 16) & 1u)) >> 16;
    return ua | (ub << 16);
}

static __device__ __forceinline__ unsigned short f2bf(float f) {
    unsigned u = __float_as_uint(f);
    return (unsigned short)((u + 0x7fffu + ((u >> 16) & 1u)) >> 16);
}

// ---------------- k0: discretization + operand layouts + lambda powers -----
__global__ __launch_bounds__(256) void k0_pre(
    const float* __restrict__ Lre, const float* __restrict__ Lim,
    const float* __restrict__ Bre, const float* __restrict__ Bim,
    const float* __restrict__ Cre, const float* __restrict__ Cim,
    const float* __restrict__ lstep,
    float* __restrict__ lam, float* __restrict__ lamLc, float* __restrict__ lamP,
    unsigned short* __restrict__ B1op, unsigned short* __restrict__ C2op)
{
    int bx = blockIdx.x;
    int t  = threadIdx.x;
    {
        int p = bx, h = t;
        float laR = Lre[p], laI = Lim[p];
        float st = expf(lstep[p]);
        float er = expf(laR * st);
        float lr = er * cosf(laI * st);
        float li = er * sinf(laI * st);
        float den = laR * laR + laI * laI;
        float nr = lr - 1.0f, ni = li;
        float cr = (nr * laR + ni * laI) / den;
        float ci = (ni * laR - nr * laI) / den;
        float br = Bre[p * H_ + h], bi = Bim[p * H_ + h];
        B1op[(2 * p) * H_ + h]     = f2bf(cr * br - ci * bi);
        B1op[(2 * p + 1) * H_ + h] = f2bf(cr * bi + ci * br);
        if (t == 0) {
            lam[2 * p] = lr; lam[2 * p + 1] = li;
            float r2 = lr*lr - li*li,  i2 = 2.f*lr*li;
            float r4 = r2*r2 - i2*i2,  i4 = 2.f*r2*i2;
            float r8 = r4*r4 - i4*i4,  i8 = 2.f*r4*i4;
            float r16 = r8*r8 - i8*i8, i16 = 2.f*r8*i8;
            float r32 = r16*r16 - i16*i16, i32 = 2.f*r16*i16;
            float r48 = r32*r16 - i32*i16, i48 = r32*i16 + i32*r16;
            float r64 = r32*r32 - i32*i32, i64 = 2.f*r32*i32;
            lamP[6*p+0] = r16; lamP[6*p+1] = i16;
            lamP[6*p+2] = r32; lamP[6*p+3] = i32;
            lamP[6*p+4] = r48; lamP[6*p+5] = i48;
            lamLc[2 * p] = r64; lamLc[2 * p + 1] = i64;
        }
    }
    {
        int h = bx, p = t;
        C2op[(size_t)h * 512 + 2 * p]     = f2bf( 2.0f * Cre[h * P_ + p]);
        C2op[(size_t)h * 512 + 2 * p + 1] = f2bf(-2.0f * Cim[h * P_ + p]);
    }
}

// ---------------- g1f: Bu GEMM (u fp32 in) + chunk-final scan --------------
__global__ __launch_bounds__(256) void g1f_gemm(
    const float* __restrict__ us,
    const unsigned short* __restrict__ B1op,
    const float* __restrict__ lam, const float* __restrict__ lamP,
    unsigned* __restrict__ Bu, float2* __restrict__ sfin)
{
    __shared__ __align__(16) char smem[35328];
    unsigned short* Al = (unsigned short*)smem;            // [128][64] swizzled
    unsigned short* Bl = (unsigned short*)(smem + 16384);  // [128][64] swizzled
    float* epl = (float*)smem;                             // [64][130] epilogue
    float2* fg = (float2*)(smem + 33280);                  // [4][64] scan partials

    int tid = threadIdx.x, w = tid >> 6, lane = tid & 63;
    int wr = w >> 1, wc = w & 1;
    int m0 = blockIdx.x * 128;
    int n0 = blockIdx.y * 128;
    int lr_ = lane & 15, lk = lane >> 4;

    f32x4 acc[4][4];
    #pragma unroll
    for (int m = 0; m < 4; ++m)
        #pragma unroll
        for (int n = 0; n < 4; ++n)
            acc[m][n] = (f32x4){0.f, 0.f, 0.f, 0.f};

    int sw8 = ((lane & 7) ^ ((lane >> 3) & 7)) * 8;
    int ar = tid >> 1, akh = (tid & 1) * 32;
    int ar7 = ar & 7;

    for (int kt = 0; kt < 4; ++kt) {
        int k0 = kt * 64;
        #pragma unroll
        for (int i = 0; i < 4; ++i) {
            int blk = i * 4 + w;
            int r = blk * 8 + (lane >> 3);
            gl_lds16(B1op + (size_t)(n0 + r) * 256 + k0 + sw8, Bl + blk * 512);
        }
        {
            const float4* up = (const float4*)(us + (size_t)(m0 + ar) * 256 + k0 + akh);
            unsigned short* arow = Al + ar * 64;
            #pragma unroll
            for (int g = 0; g < 4; ++g) {
                float4 v0 = up[g * 2], v1 = up[g * 2 + 1];
                uint4 o;
                o.x = pack_bf16x2(v0.x, v0.y); o.y = pack_bf16x2(v0.z, v0.w);
                o.z = pack_bf16x2(v1.x, v1.y); o.w = pack_bf16x2(v1.z, v1.w);
                int gg = (tid & 1) * 4 + g;
                *(uint4*)(arow + ((gg ^ ar7) * 8)) = o;
            }
        }
        __syncthreads();
        #pragma unroll
        for (int kk = 0; kk < 2; ++kk) {
            short8v a_[4], b_[4];
            #pragma unroll
            for (int m = 0; m < 4; ++m) {
                int row = wr * 64 + m * 16 + lr_;
                a_[m] = *(const short8v*)&Al[row * 64 + (((lk + 4 * kk) ^ (lr_ & 7)) * 8)];
            }
            #pragma unroll
            for (int n = 0; n < 4; ++n) {
                int row = wc * 64 + n * 16 + lr_;
                b_[n] = *(const short8v*)&Bl[row * 64 + (((lk + 4 * kk) ^ (lr_ & 7)) * 8)];
            }
            #pragma unroll
            for (int m = 0; m < 4; ++m)
                #pragma unroll
                for (int n = 0; n < 4; ++n)
                    acc[m][n] = __builtin_amdgcn_mfma_f32_16x16x32_bf16(a_[m], b_[n], acc[m][n], 0, 0, 0);
        }
        __syncthreads();
    }

    int n0d = blockIdx.y * 64;
    int bl = m0 >> 12;
    int cl = (m0 & (L_ - 1)) >> 6;
    int q = lane;
    int g = w;
    int p_glob = n0d + q;
    float lamr = lam[2 * p_glob], lami = lam[2 * p_glob + 1];

    #pragma unroll
    for (int ph = 0; ph < 2; ++ph) {
        if (wr == ph) {
            #pragma unroll
            for (int m = 0; m < 4; ++m)
                #pragma unroll
                for (int n = 0; n < 4; ++n)
                    #pragma unroll
                    for (int i = 0; i < 4; ++i) {
                        int r = m * 16 + lk * 4 + i;
                        int c = wc * 64 + n * 16 + lr_;
                        epl[r * 130 + c] = acc[m][n][i];
                    }
        }
        __syncthreads();
        #pragma unroll
        for (int it = 0; it < 16; ++it) {
            int r = it * 4 + w;
            float2 v = *(const float2*)&epl[r * 130 + 2 * lane];
            Bu[(size_t)(m0 + ph * 64 + r) * 256 + n0d + lane] = pack_bf16x2(v.x, v.y);
        }
        {
            float fr = 0.f, fi = 0.f;
            const float* col = epl + 2 * q;
            #pragma unroll
            for (int r = g * 16; r < g * 16 + 16; ++r) {
                float2 bv = *(const float2*)&col[r * 130];
                float nr = lamr * fr - lami * fi + bv.x;
                float ni = lamr * fi + lami * fr + bv.y;
                fr = nr; fi = ni;
            }
            fg[g * 64 + q] = make_float2(fr, fi);
        }
        __syncthreads();
        if (g == 0) {
            float2 f0 = fg[q], f1 = fg[64 + q], f2 = fg[128 + q], f3 = fg[192 + q];
            const float* lp = lamP + 6 * p_glob;
            float rr = f3.x + lp[4] * f0.x - lp[5] * f0.y
                            + lp[2] * f1.x - lp[3] * f1.y
                            + lp[0] * f2.x - lp[1] * f2.y;
            float ri = f3.y + lp[4] * f0.y + lp[5] * f0.x
                            + lp[2] * f1.y + lp[3] * f1.x
                            + lp[0] * f2.y + lp[1] * f2.x;
            sfin[(bl * NC + cl + ph) * P_ + p_glob] = make_float2(rr, ri);
        }
        __syncthreads();
    }
}

// ---------------- s2: cross-chunk chain ----------------
__global__ __launch_bounds__(256) void s2_chain(
    const float* __restrict__ lamLc, const float2* __restrict__ sfin,
    float2* __restrict__ sinv)
{
    int bl = blockIdx.x;
    int p = threadIdx.x;
    float ar = lamLc[2 * p], ai = lamLc[2 * p + 1];
    float sr = 0.f, si = 0.f;
    #pragma unroll 8
    for (int c = 0; c < NC; ++c) {
        sinv[(bl * NC + c) * P_ + p] = make_float2(sr, si);
        float2 f = sfin[(bl * NC + c) * P_ + p];
        float nr = ar * sr - ai * si + f.x;
        float ni = ar * si + ai * sr + f.y;
        sr = nr; si = ni;
    }
}

// ---------------- g2h: per-chunk scan + output GEMM (h-split) + D*u --------
// block = 1 chunk (64 l-rows) x 128 h-cols; grid (SEG*NC, 2); 2 blocks/CU.
__global__ __launch_bounds__(256) void g2h_gemm(
    const unsigned* __restrict__ Bu,
    const unsigned short* __restrict__ C2op,
    const float* __restrict__ lam, const float2* __restrict__ sinv,
    const float* __restrict__ useg, const float* __restrict__ Dv,
    float* __restrict__ yseg)
{
    __shared__ __align__(16) char xs[64 * 1024];   // 64 rows x 512 bf16, swizzled
    int tid = threadIdx.x, w = tid >> 6, lane = tid & 63;
    int c = blockIdx.x & (NC - 1), bl = blockIdx.x >> 6;
    int hh = blockIdx.y;                           // 0..1: h-half

    // phase 1: scan this chunk, write x (bf16) to swizzled LDS
    {
        int p = tid;
        float lr = lam[2 * p], li = lam[2 * p + 1];
        float2 s0 = sinv[(bl * NC + c) * P_ + p];
        float xr = s0.x, xi = s0.y;
        const unsigned* bp = Bu + ((size_t)(bl * L_ + c * LC)) * 256 + p;
        int T = p >> 5, qd = (p & 31) >> 2, pos = p & 3;
        char* base = xs + T * 8192 + (pos << 2);
        #pragma unroll 8
        for (int j = 0; j < LC; ++j) {
            unsigned wv = bp[(size_t)j * 256];
            float ur = __uint_as_float(wv << 16);
            float ui = __uint_as_float(wv & 0xffff0000u);
            float nr = lr * xr - li * xi + ur;
            float ni = lr * xi + li * xr + ui;
            xr = nr; xi = ni;
            *(unsigned*)(base + j * 128 + ((qd ^ (j & 7)) << 4)) = pack_bf16x2(xr, xi);
        }
    }
    __syncthreads();

    // phase 2: GEMM  y[64][128] = x[64][512] * C2op^T[512][128(half)]
    int lr_ = lane & 15, lk = lane >> 4;
    int r7 = lr_ & 7;
    int h0 = hh * 128 + w * 32;
    f32x4 acc[4][2];
    #pragma unroll
    for (int m = 0; m < 4; ++m)
        #pragma unroll
        for (int n = 0; n < 2; ++n)
            acc[m][n] = (f32x4){0.f, 0.f, 0.f, 0.f};

    for (int kt = 0; kt < 16; ++kt) {
        int T = kt >> 1, q2 = (kt & 1) * 4 + lk;
        short8v a_[4], b_[2];
        #pragma unroll
        for (int m = 0; m < 4; ++m) {
            int row = m * 16 + lr_;
            a_[m] = *(const short8v*)(xs + T * 8192 + row * 128 + ((q2 ^ r7) << 4));
        }
        #pragma unroll
        for (int n = 0; n < 2; ++n)
            b_[n] = *(const short8v*)&C2op[(size_t)(h0 + n * 16 + lr_) * 512 + kt * 32 + lk * 8];
        #pragma unroll
        for (int m = 0; m < 4; ++m)
            #pragma unroll
            for (int n = 0; n < 2; ++n)
                acc[m][n] = __builtin_amdgcn_mfma_f32_16x16x32_bf16(a_[m], b_[n], acc[m][n], 0, 0, 0);
    }

    float d_[2];
    #pragma unroll
    for (int n = 0; n < 2; ++n) d_[n] = Dv[h0 + n * 16 + lr_];
    #pragma unroll
    for (int m = 0; m < 4; ++m)
        #pragma unroll
        for (int n = 0; n < 2; ++n)
            #pragma unroll
            for (int i = 0; i < 4; ++i) {
                int rl = m * 16 + lk * 4 + i;
                int col = h0 + n * 16 + lr_;
                size_t off = ((size_t)(bl * L_ + c * LC + rl)) * 256 + col;
                yseg[off] = acc[m][n][i] + d_[n] * useg[off];
            }
}

// ---------------- launch ----------------
extern "C" void kernel_launch(void* const* d_in, const int* in_sizes, int n_in,
                              void* d_out, int out_size, void* d_ws, size_t ws_size,
                              hipStream_t stream) {
    (void)in_sizes; (void)n_in; (void)out_size; (void)ws_size;
    const float* u    = (const float*)d_in[0];
    const float* Lre  = (const float*)d_in[1];
    const float* Lim  = (const float*)d_in[2];
    const float* Bre  = (const float*)d_in[3];
    const float* Bim  = (const float*)d_in[4];
    const float* Cre  = (const float*)d_in[5];
    const float* Cim  = (const float*)d_in[6];
    const float* Dv   = (const float*)d_in[7];
    const float* lstep= (const float*)d_in[8];

    char* w0 = (char*)d_ws;
    float* lam   = (float*)w0;  w0 += 2048;
    float* lamLc = (float*)w0;  w0 += 2048;
    float* lamP  = (float*)w0;  w0 += 6 * P_ * 4;
    unsigned short* B1op = (unsigned short*)w0; w0 += 512 * 256 * 2;
    unsigned short* C2op = (unsigned short*)w0; w0 += 256 * 512 * 2;
    float2* sfin = (float2*)w0; w0 += (size_t)SEG * NC * P_ * 8;
    float2* sinv = (float2*)w0; w0 += (size_t)SEG * NC * P_ * 8;
    unsigned* Bu = (unsigned*)w0; w0 += (size_t)MSEG * 256 * 4;

    k0_pre<<<256, 256, 0, stream>>>(Lre, Lim, Bre, Bim, Cre, Cim, lstep,
                                    lam, lamLc, lamP, B1op, C2op);
    for (int s = 0; s < NSEG; ++s) {
        const float* us = u + (size_t)s * MSEG * H_;
        float* ys = (float*)d_out + (size_t)s * MSEG * H_;
        g1f_gemm<<<dim3(MSEG / 128, 4), 256, 0, stream>>>(us, B1op, lam, lamP, Bu, sfin);
        s2_chain<<<SEG, 256, 0, stream>>>(lamLc, sfin, sinv);
        g2h_gemm<<<dim3(SEG * NC, 2), 256, 0, stream>>>(Bu, C2op, lam, sinv, us, Dv, ys);
    }
}

// Round 5
// 162.043 us; speedup vs baseline: 1.3667x; 1.2066x over previous
//
#include <hip/hip_runtime.h>
#include <hip/hip_bf16.h>

// S5 layer, fused MFMA pipeline with runtime segmentation (by ws_size):
//   k0  : discretization, bf16 operand layouts, lambda power tables
//   g1f : u(fp32)->bf16 reg-staged GEMM -> Bu (packed bf16) + chunk-final states
//   s2  : cross-chunk state chain (sfin -> sinv)
//   g2f : per-chunk scan + full-H output GEMM + D*u   (nb >= 8: grid >= 512)
//   g2h : per-chunk scan + h-split output GEMM + D*u  (nb == 4 fallback)

#define P_ 256
#define H_ 256
#define B_ 16
#define L_ 4096
#define LC 64
#define NC (L_/LC)          // 64 chunks per batch

typedef __attribute__((ext_vector_type(8))) short short8v;
typedef __attribute__((ext_vector_type(4))) float f32x4;

#define GLOBAL_AS __attribute__((address_space(1)))
#define LDS_AS __attribute__((address_space(3)))

static __device__ __forceinline__ void gl_lds16(const void* g, void* l) {
    __builtin_amdgcn_global_load_lds((const GLOBAL_AS unsigned char*)g,
                                     (LDS_AS unsigned char*)l, 16, 0, 0);
}

static __device__ __forceinline__ unsigned pack_bf16x2(float a, float b) {
    unsigned ua = __float_as_uint(a);
    unsigned ub = __float_as_uint(b);
    ua = (ua + 0x7fffu + ((ua >> 16) & 1u)) >> 16;   // RNE
    ub = (ub + 0x7fffu + ((ub >> 16) & 1u)) >> 16;
    return ua | (ub << 16);
}

static __device__ __forceinline__ unsigned short f2bf(float f) {
    unsigned u = __float_as_uint(f);
    return (unsigned short)((u + 0x7fffu + ((u >> 16) & 1u)) >> 16);
}

// ---------------- k0: discretization + operand layouts + lambda powers -----
__global__ __launch_bounds__(256) void k0_pre(
    const float* __restrict__ Lre, const float* __restrict__ Lim,
    const float* __restrict__ Bre, const float* __restrict__ Bim,
    const float* __restrict__ Cre, const float* __restrict__ Cim,
    const float* __restrict__ lstep,
    float* __restrict__ lam, float* __restrict__ lamLc, float* __restrict__ lamP,
    unsigned short* __restrict__ B1op, unsigned short* __restrict__ C2op)
{
    int bx = blockIdx.x;
    int t  = threadIdx.x;
    {
        int p = bx, h = t;
        float laR = Lre[p], laI = Lim[p];
        float st = expf(lstep[p]);
        float er = expf(laR * st);
        float lr = er * cosf(laI * st);
        float li = er * sinf(laI * st);
        float den = laR * laR + laI * laI;
        float nr = lr - 1.0f, ni = li;
        float cr = (nr * laR + ni * laI) / den;
        float ci = (ni * laR - nr * laI) / den;
        float br = Bre[p * H_ + h], bi = Bim[p * H_ + h];
        B1op[(2 * p) * H_ + h]     = f2bf(cr * br - ci * bi);
        B1op[(2 * p + 1) * H_ + h] = f2bf(cr * bi + ci * br);
        if (t == 0) {
            lam[2 * p] = lr; lam[2 * p + 1] = li;
            float r2 = lr*lr - li*li,  i2 = 2.f*lr*li;
            float r4 = r2*r2 - i2*i2,  i4 = 2.f*r2*i2;
            float r8 = r4*r4 - i4*i4,  i8 = 2.f*r4*i4;
            float r16 = r8*r8 - i8*i8, i16 = 2.f*r8*i8;
            float r32 = r16*r16 - i16*i16, i32 = 2.f*r16*i16;
            float r48 = r32*r16 - i32*i16, i48 = r32*i16 + i32*r16;
            float r64 = r32*r32 - i32*i32, i64 = 2.f*r32*i32;
            lamP[6*p+0] = r16; lamP[6*p+1] = i16;
            lamP[6*p+2] = r32; lamP[6*p+3] = i32;
            lamP[6*p+4] = r48; lamP[6*p+5] = i48;
            lamLc[2 * p] = r64; lamLc[2 * p + 1] = i64;
        }
    }
    {
        int h = bx, p = t;
        C2op[(size_t)h * 512 + 2 * p]     = f2bf( 2.0f * Cre[h * P_ + p]);
        C2op[(size_t)h * 512 + 2 * p + 1] = f2bf(-2.0f * Cim[h * P_ + p]);
    }
}

// ---------------- g1f: Bu GEMM (u fp32 in) + chunk-final scan --------------
// grid: (nb*L/128, 4); segment-local pointers.
__global__ __launch_bounds__(256) void g1f_gemm(
    const float* __restrict__ us,
    const unsigned short* __restrict__ B1op,
    const float* __restrict__ lam, const float* __restrict__ lamP,
    unsigned* __restrict__ Bu, float2* __restrict__ sfin)
{
    __shared__ __align__(16) char smem[35328];
    unsigned short* Al = (unsigned short*)smem;            // [128][64] swizzled
    unsigned short* Bl = (unsigned short*)(smem + 16384);  // [128][64] swizzled
    float* epl = (float*)smem;                             // [64][130] epilogue
    float2* fg = (float2*)(smem + 33280);                  // [4][64] scan partials

    int tid = threadIdx.x, w = tid >> 6, lane = tid & 63;
    int wr = w >> 1, wc = w & 1;
    int m0 = blockIdx.x * 128;
    int n0 = blockIdx.y * 128;
    int lr_ = lane & 15, lk = lane >> 4;

    f32x4 acc[4][4];
    #pragma unroll
    for (int m = 0; m < 4; ++m)
        #pragma unroll
        for (int n = 0; n < 4; ++n)
            acc[m][n] = (f32x4){0.f, 0.f, 0.f, 0.f};

    int sw8 = ((lane & 7) ^ ((lane >> 3) & 7)) * 8;
    int ar = tid >> 1, akh = (tid & 1) * 32;
    int ar7 = ar & 7;

    for (int kt = 0; kt < 4; ++kt) {
        int k0 = kt * 64;
        #pragma unroll
        for (int i = 0; i < 4; ++i) {
            int blk = i * 4 + w;
            int r = blk * 8 + (lane >> 3);
            gl_lds16(B1op + (size_t)(n0 + r) * 256 + k0 + sw8, Bl + blk * 512);
        }
        {
            const float4* up = (const float4*)(us + (size_t)(m0 + ar) * 256 + k0 + akh);
            unsigned short* arow = Al + ar * 64;
            #pragma unroll
            for (int g = 0; g < 4; ++g) {
                float4 v0 = up[g * 2], v1 = up[g * 2 + 1];
                uint4 o;
                o.x = pack_bf16x2(v0.x, v0.y); o.y = pack_bf16x2(v0.z, v0.w);
                o.z = pack_bf16x2(v1.x, v1.y); o.w = pack_bf16x2(v1.z, v1.w);
                int gg = (tid & 1) * 4 + g;
                *(uint4*)(arow + ((gg ^ ar7) * 8)) = o;
            }
        }
        __syncthreads();
        #pragma unroll
        for (int kk = 0; kk < 2; ++kk) {
            short8v a_[4], b_[4];
            #pragma unroll
            for (int m = 0; m < 4; ++m) {
                int row = wr * 64 + m * 16 + lr_;
                a_[m] = *(const short8v*)&Al[row * 64 + (((lk + 4 * kk) ^ (lr_ & 7)) * 8)];
            }
            #pragma unroll
            for (int n = 0; n < 4; ++n) {
                int row = wc * 64 + n * 16 + lr_;
                b_[n] = *(const short8v*)&Bl[row * 64 + (((lk + 4 * kk) ^ (lr_ & 7)) * 8)];
            }
            #pragma unroll
            for (int m = 0; m < 4; ++m)
                #pragma unroll
                for (int n = 0; n < 4; ++n)
                    acc[m][n] = __builtin_amdgcn_mfma_f32_16x16x32_bf16(a_[m], b_[n], acc[m][n], 0, 0, 0);
        }
        __syncthreads();
    }

    int n0d = blockIdx.y * 64;
    int bl = m0 >> 12;
    int cl = (m0 & (L_ - 1)) >> 6;
    int q = lane;
    int g = w;
    int p_glob = n0d + q;
    float lamr = lam[2 * p_glob], lami = lam[2 * p_glob + 1];

    #pragma unroll
    for (int ph = 0; ph < 2; ++ph) {
        if (wr == ph) {
            #pragma unroll
            for (int m = 0; m < 4; ++m)
                #pragma unroll
                for (int n = 0; n < 4; ++n)
                    #pragma unroll
                    for (int i = 0; i < 4; ++i) {
                        int r = m * 16 + lk * 4 + i;
                        int c = wc * 64 + n * 16 + lr_;
                        epl[r * 130 + c] = acc[m][n][i];
                    }
        }
        __syncthreads();
        #pragma unroll
        for (int it = 0; it < 16; ++it) {
            int r = it * 4 + w;
            float2 v = *(const float2*)&epl[r * 130 + 2 * lane];
            Bu[(size_t)(m0 + ph * 64 + r) * 256 + n0d + lane] = pack_bf16x2(v.x, v.y);
        }
        // chunk-final scan from the SAME bf16-rounded values g2 will re-scan
        {
            float fr = 0.f, fi = 0.f;
            const float* col = epl + 2 * q;
            #pragma unroll
            for (int r = g * 16; r < g * 16 + 16; ++r) {
                float2 bv = *(const float2*)&col[r * 130];
                unsigned wq = pack_bf16x2(bv.x, bv.y);
                float ur = __uint_as_float(wq << 16);
                float ui = __uint_as_float(wq & 0xffff0000u);
                float nr = lamr * fr - lami * fi + ur;
                float ni = lamr * fi + lami * fr + ui;
                fr = nr; fi = ni;
            }
            fg[g * 64 + q] = make_float2(fr, fi);
        }
        __syncthreads();
        if (g == 0) {
            float2 f0 = fg[q], f1 = fg[64 + q], f2 = fg[128 + q], f3 = fg[192 + q];
            const float* lp = lamP + 6 * p_glob;
            float rr = f3.x + lp[4] * f0.x - lp[5] * f0.y
                            + lp[2] * f1.x - lp[3] * f1.y
                            + lp[0] * f2.x - lp[1] * f2.y;
            float ri = f3.y + lp[4] * f0.y + lp[5] * f0.x
                            + lp[2] * f1.y + lp[3] * f1.x
                            + lp[0] * f2.y + lp[1] * f2.x;
            sfin[(bl * NC + cl + ph) * P_ + p_glob] = make_float2(rr, ri);
        }
        __syncthreads();
    }
}

// ---------------- s2: cross-chunk chain (grid = nb blocks) -----------------
__global__ __launch_bounds__(256) void s2_chain(
    const float* __restrict__ lamLc, const float2* __restrict__ sfin,
    float2* __restrict__ sinv)
{
    int bl = blockIdx.x;
    int p = threadIdx.x;
    float ar = lamLc[2 * p], ai = lamLc[2 * p + 1];
    float sr = 0.f, si = 0.f;
    #pragma unroll 8
    for (int c = 0; c < NC; ++c) {
        sinv[(bl * NC + c) * P_ + p] = make_float2(sr, si);
        float2 f = sfin[(bl * NC + c) * P_ + p];
        float nr = ar * sr - ai * si + f.x;
        float ni = ar * si + ai * sr + f.y;
        sr = nr; si = ni;
    }
}

// ---------------- g2f: per-chunk scan + full-H output GEMM + D*u -----------
// block = 1 chunk (64 rows) x H=256; grid = nb*NC; 2 blocks/CU (64KB LDS).
__global__ __launch_bounds__(256) void g2f_gemm(
    const unsigned* __restrict__ Bu,
    const unsigned short* __restrict__ C2op,
    const float* __restrict__ lam, const float2* __restrict__ sinv,
    const float* __restrict__ useg, const float* __restrict__ Dv,
    float* __restrict__ yseg)
{
    __shared__ __align__(16) char xs[64 * 1024];
    int tid = threadIdx.x, w = tid >> 6, lane = tid & 63;
    int c = blockIdx.x & (NC - 1), bl = blockIdx.x >> 6;

    {
        int p = tid;
        float lr = lam[2 * p], li = lam[2 * p + 1];
        float2 s0 = sinv[(bl * NC + c) * P_ + p];
        float xr = s0.x, xi = s0.y;
        const unsigned* bp = Bu + ((size_t)(bl * L_ + c * LC)) * 256 + p;
        int T = p >> 5, qd = (p & 31) >> 2, pos = p & 3;
        char* base = xs + T * 8192 + (pos << 2);
        #pragma unroll 8
        for (int j = 0; j < LC; ++j) {
            unsigned wv = bp[(size_t)j * 256];
            float ur = __uint_as_float(wv << 16);
            float ui = __uint_as_float(wv & 0xffff0000u);
            float nr = lr * xr - li * xi + ur;
            float ni = lr * xi + li * xr + ui;
            xr = nr; xi = ni;
            *(unsigned*)(base + j * 128 + ((qd ^ (j & 7)) << 4)) = pack_bf16x2(xr, xi);
        }
    }
    __syncthreads();

    int lr_ = lane & 15, lk = lane >> 4;
    int r7 = lr_ & 7;
    int h0 = w * 64;
    f32x4 acc[4][4];
    #pragma unroll
    for (int m = 0; m < 4; ++m)
        #pragma unroll
        for (int n = 0; n < 4; ++n)
            acc[m][n] = (f32x4){0.f, 0.f, 0.f, 0.f};

    for (int kt = 0; kt < 16; ++kt) {
        int T = kt >> 1, q2 = (kt & 1) * 4 + lk;
        short8v a_[4], b_[4];
        #pragma unroll
        for (int m = 0; m < 4; ++m) {
            int row = m * 16 + lr_;
            a_[m] = *(const short8v*)(xs + T * 8192 + row * 128 + ((q2 ^ r7) << 4));
        }
        #pragma unroll
        for (int n = 0; n < 4; ++n)
            b_[n] = *(const short8v*)&C2op[(size_t)(h0 + n * 16 + lr_) * 512 + kt * 32 + lk * 8];
        #pragma unroll
        for (int m = 0; m < 4; ++m)
            #pragma unroll
            for (int n = 0; n < 4; ++n)
                acc[m][n] = __builtin_amdgcn_mfma_f32_16x16x32_bf16(a_[m], b_[n], acc[m][n], 0, 0, 0);
    }

    float d_[4];
    #pragma unroll
    for (int n = 0; n < 4; ++n) d_[n] = Dv[h0 + n * 16 + lr_];
    #pragma unroll
    for (int m = 0; m < 4; ++m)
        #pragma unroll
        for (int n = 0; n < 4; ++n)
            #pragma unroll
            for (int i = 0; i < 4; ++i) {
                int rl = m * 16 + lk * 4 + i;
                int col = h0 + n * 16 + lr_;
                size_t off = ((size_t)(bl * L_ + c * LC + rl)) * 256 + col;
                yseg[off] = acc[m][n][i] + d_[n] * useg[off];
            }
}

// ---------------- g2h: per-chunk scan + h-split GEMM (nb==4 fallback) ------
__global__ __launch_bounds__(256) void g2h_gemm(
    const unsigned* __restrict__ Bu,
    const unsigned short* __restrict__ C2op,
    const float* __restrict__ lam, const float2* __restrict__ sinv,
    const float* __restrict__ useg, const float* __restrict__ Dv,
    float* __restrict__ yseg)
{
    __shared__ __align__(16) char xs[64 * 1024];
    int tid = threadIdx.x, w = tid >> 6, lane = tid & 63;
    int c = blockIdx.x & (NC - 1), bl = blockIdx.x >> 6;
    int hh = blockIdx.y;

    {
        int p = tid;
        float lr = lam[2 * p], li = lam[2 * p + 1];
        float2 s0 = sinv[(bl * NC + c) * P_ + p];
        float xr = s0.x, xi = s0.y;
        const unsigned* bp = Bu + ((size_t)(bl * L_ + c * LC)) * 256 + p;
        int T = p >> 5, qd = (p & 31) >> 2, pos = p & 3;
        char* base = xs + T * 8192 + (pos << 2);
        #pragma unroll 8
        for (int j = 0; j < LC; ++j) {
            unsigned wv = bp[(size_t)j * 256];
            float ur = __uint_as_float(wv << 16);
            float ui = __uint_as_float(wv & 0xffff0000u);
            float nr = lr * xr - li * xi + ur;
            float ni = lr * xi + li * xr + ui;
            xr = nr; xi = ni;
            *(unsigned*)(base + j * 128 + ((qd ^ (j & 7)) << 4)) = pack_bf16x2(xr, xi);
        }
    }
    __syncthreads();

    int lr_ = lane & 15, lk = lane >> 4;
    int r7 = lr_ & 7;
    int h0 = hh * 128 + w * 32;
    f32x4 acc[4][2];
    #pragma unroll
    for (int m = 0; m < 4; ++m)
        #pragma unroll
        for (int n = 0; n < 2; ++n)
            acc[m][n] = (f32x4){0.f, 0.f, 0.f, 0.f};

    for (int kt = 0; kt < 16; ++kt) {
        int T = kt >> 1, q2 = (kt & 1) * 4 + lk;
        short8v a_[4], b_[2];
        #pragma unroll
        for (int m = 0; m < 4; ++m) {
            int row = m * 16 + lr_;
            a_[m] = *(const short8v*)(xs + T * 8192 + row * 128 + ((q2 ^ r7) << 4));
        }
        #pragma unroll
        for (int n = 0; n < 2; ++n)
            b_[n] = *(const short8v*)&C2op[(size_t)(h0 + n * 16 + lr_) * 512 + kt * 32 + lk * 8];
        #pragma unroll
        for (int m = 0; m < 4; ++m)
            #pragma unroll
            for (int n = 0; n < 2; ++n)
                acc[m][n] = __builtin_amdgcn_mfma_f32_16x16x32_bf16(a_[m], b_[n], acc[m][n], 0, 0, 0);
    }

    float d_[2];
    #pragma unroll
    for (int n = 0; n < 2; ++n) d_[n] = Dv[h0 + n * 16 + lr_];
    #pragma unroll
    for (int m = 0; m < 4; ++m)
        #pragma unroll
        for (int n = 0; n < 2; ++n)
            #pragma unroll
            for (int i = 0; i < 4; ++i) {
                int rl = m * 16 + lk * 4 + i;
                int col = h0 + n * 16 + lr_;
                size_t off = ((size_t)(bl * L_ + c * LC + rl)) * 256 + col;
                yseg[off] = acc[m][n][i] + d_[n] * useg[off];
            }
}

// ---------------- launch ----------------
extern "C" void kernel_launch(void* const* d_in, const int* in_sizes, int n_in,
                              void* d_out, int out_size, void* d_ws, size_t ws_size,
                              hipStream_t stream) {
    (void)in_sizes; (void)n_in; (void)out_size;
    const float* u    = (const float*)d_in[0];
    const float* Lre  = (const float*)d_in[1];
    const float* Lim  = (const float*)d_in[2];
    const float* Bre  = (const float*)d_in[3];
    const float* Bim  = (const float*)d_in[4];
    const float* Cre  = (const float*)d_in[5];
    const float* Cim  = (const float*)d_in[6];
    const float* Dv   = (const float*)d_in[7];
    const float* lstep= (const float*)d_in[8];

    // pick largest segment size the workspace allows
    const size_t fixed = 2048 + 2048 + 6 * P_ * 4
                       + (size_t)512 * 256 * 2 + (size_t)256 * 512 * 2;
    int nb = 4;
    {
        size_t per16 = (size_t)16 * (NC * P_ * 8 * 2 + L_ * 256 * 4);
        size_t per8  = per16 / 2;
        if (ws_size >= fixed + per16 + 4096) nb = 16;
        else if (ws_size >= fixed + per8 + 4096) nb = 8;
    }
    int nseg = B_ / nb;

    char* w0 = (char*)d_ws;
    float* lam   = (float*)w0;  w0 += 2048;
    float* lamLc = (float*)w0;  w0 += 2048;
    float* lamP  = (float*)w0;  w0 += 6 * P_ * 4;
    unsigned short* B1op = (unsigned short*)w0; w0 += 512 * 256 * 2;
    unsigned short* C2op = (unsigned short*)w0; w0 += 256 * 512 * 2;
    float2* sfin = (float2*)w0; w0 += (size_t)nb * NC * P_ * 8;
    float2* sinv = (float2*)w0; w0 += (size_t)nb * NC * P_ * 8;
    unsigned* Bu = (unsigned*)w0;

    k0_pre<<<256, 256, 0, stream>>>(Lre, Lim, Bre, Bim, Cre, Cim, lstep,
                                    lam, lamLc, lamP, B1op, C2op);
    for (int s = 0; s < nseg; ++s) {
        const float* us = u + (size_t)s * nb * L_ * H_;
        float* ys = (float*)d_out + (size_t)s * nb * L_ * H_;
        g1f_gemm<<<dim3(nb * L_ / 128, 4), 256, 0, stream>>>(us, B1op, lam, lamP, Bu, sfin);
        s2_chain<<<nb, 256, 0, stream>>>(lamLc, sfin, sinv);
        if (nb >= 8)
            g2f_gemm<<<nb * NC, 256, 0, stream>>>(Bu, C2op, lam, sinv, us, Dv, ys);
        else
            g2h_gemm<<<dim3(nb * NC, 2), 256, 0, stream>>>(Bu, C2op, lam, sinv, us, Dv, ys);
    }
}

// Round 6
// 141.217 us; speedup vs baseline: 1.5683x; 1.1475x over previous
//
#include <hip/hip_runtime.h>
#include <hip/hip_bf16.h>

// S5 layer, fused MFMA pipeline (runtime segmentation by ws_size):
//   k0  : discretization, bf16 operands, lambda power table (16 f32/p)
//   g1c : per-chunk full-N Bu GEMM (u fp32 -> bf16, staged once) ->
//         BuT transposed [chunk][p][64] packed bf16 + in-register chunk finals
//   s2  : cross-chunk state chain (sfin -> sinv)
//   g2f : per-chunk scan (BuT contiguous) + full-H output GEMM + D*u

#define P_ 256
#define H_ 256
#define B_ 16
#define L_ 4096
#define LC 64
#define NC (L_/LC)          // 64 chunks per batch

typedef __attribute__((ext_vector_type(8))) short short8v;
typedef __attribute__((ext_vector_type(4))) float f32x4;

static __device__ __forceinline__ unsigned pack_bf16x2(float a, float b) {
    unsigned ua = __float_as_uint(a);
    unsigned ub = __float_as_uint(b);
    ua = (ua + 0x7fffu + ((ua >> 16) & 1u)) >> 16;   // RNE
    ub = (ub + 0x7fffu + ((ub >> 16) & 1u)) >> 16;
    return ua | (ub << 16);
}

static __device__ __forceinline__ unsigned short f2bf(float f) {
    unsigned u = __float_as_uint(f);
    return (unsigned short)((u + 0x7fffu + ((u >> 16) & 1u)) >> 16);
}

// ---------------- k0: discretization + operand layouts + lambda powers -----
// B1op [2P][H] bf16: row 2p = Bbar_re[p][:], row 2p+1 = Bbar_im[p][:]
// C2op [H][2P] bf16: [h][2p] = 2*Cre[h][p], [h][2p+1] = -2*Cim[h][p]
// lamP [P][16] f32: {l,l4,l8,l12,l16,l32,l48,(pad)} as (re,im) pairs
__global__ __launch_bounds__(256) void k0_pre(
    const float* __restrict__ Lre, const float* __restrict__ Lim,
    const float* __restrict__ Bre, const float* __restrict__ Bim,
    const float* __restrict__ Cre, const float* __restrict__ Cim,
    const float* __restrict__ lstep,
    float* __restrict__ lam, float* __restrict__ lamLc, float* __restrict__ lamP,
    unsigned short* __restrict__ B1op, unsigned short* __restrict__ C2op)
{
    int bx = blockIdx.x;
    int t  = threadIdx.x;
    {
        int p = bx, h = t;
        float laR = Lre[p], laI = Lim[p];
        float st = expf(lstep[p]);
        float er = expf(laR * st);
        float lr = er * cosf(laI * st);
        float li = er * sinf(laI * st);
        float den = laR * laR + laI * laI;
        float nr = lr - 1.0f, ni = li;
        float cr = (nr * laR + ni * laI) / den;
        float ci = (ni * laR - nr * laI) / den;
        float br = Bre[p * H_ + h], bi = Bim[p * H_ + h];
        B1op[(2 * p) * H_ + h]     = f2bf(cr * br - ci * bi);
        B1op[(2 * p + 1) * H_ + h] = f2bf(cr * bi + ci * br);
        if (t == 0) {
            lam[2 * p] = lr; lam[2 * p + 1] = li;
            float r2 = lr*lr - li*li,   i2 = 2.f*lr*li;
            float r4 = r2*r2 - i2*i2,   i4 = 2.f*r2*i2;
            float r8 = r4*r4 - i4*i4,   i8 = 2.f*r4*i4;
            float r12 = r8*r4 - i8*i4,  i12 = r8*i4 + i8*r4;
            float r16 = r8*r8 - i8*i8,  i16 = 2.f*r8*i8;
            float r32 = r16*r16 - i16*i16, i32 = 2.f*r16*i16;
            float r48 = r32*r16 - i32*i16, i48 = r32*i16 + i32*r16;
            float r64 = r32*r32 - i32*i32, i64 = 2.f*r32*i32;
            float* lp = lamP + 16 * p;
            lp[0] = lr;  lp[1] = li;
            lp[2] = r4;  lp[3] = i4;
            lp[4] = r8;  lp[5] = i8;
            lp[6] = r12; lp[7] = i12;
            lp[8] = r16; lp[9] = i16;
            lp[10] = r32; lp[11] = i32;
            lp[12] = r48; lp[13] = i48;
            lp[14] = 0.f; lp[15] = 0.f;
            lamLc[2 * p] = r64; lamLc[2 * p + 1] = i64;
        }
    }
    {
        int h = bx, p = t;
        C2op[(size_t)h * 512 + 2 * p]     = f2bf( 2.0f * Cre[h * P_ + p]);
        C2op[(size_t)h * 512 + 2 * p + 1] = f2bf(-2.0f * Cim[h * P_ + p]);
    }
}

// ---------------- g1c: chunk Bu GEMM (full N=512) + in-reg chunk finals ----
// block = 64 u-rows (one chunk) x N=512; A staged once in 32KB LDS;
// B1op fragments read from L2. Out: BuT [chunk][256 p][64 j] dwords + sfin.
__global__ __launch_bounds__(256, 2) void g1c_gemm(
    const float* __restrict__ us,
    const unsigned short* __restrict__ B1op,
    const float* __restrict__ lamP,
    unsigned* __restrict__ BuT, float2* __restrict__ sfin)
{
    __shared__ __align__(16) char As[32768];   // 4 T-tiles x [64 rows][8x16B granules]
    int tid = threadIdx.x, w = tid >> 6, lane = tid & 63;
    int ci = blockIdx.x;                       // chunk index

    // stage A: u fp32 -> bf16, swizzled; coalesced 1KB/wave loads
    {
        const float4* ub = (const float4*)(us + (size_t)ci * 64 * 256);
        #pragma unroll
        for (int jj = 0; jj < 16; ++jj) {
            int f = jj * 256 + tid;
            int r = f >> 6, c4 = f & 63;
            float4 v = ub[f];
            uint2 o;
            o.x = pack_bf16x2(v.x, v.y);
            o.y = pack_bf16x2(v.z, v.w);
            int pos = (((c4 >> 1) & 7) ^ (r & 7)) ^ (((c4 >> 5) & 1) << 2);
            *(uint2*)(As + (c4 >> 4) * 8192 + r * 128 + (pos << 4) + (c4 & 1) * 8) = o;
        }
    }
    __syncthreads();

    int lr_ = lane & 15, lk = lane >> 4, r7 = lr_ & 7;
    f32x4 acc[4][8];
    #pragma unroll
    for (int m = 0; m < 4; ++m)
        #pragma unroll
        for (int n = 0; n < 8; ++n)
            acc[m][n] = (f32x4){0.f, 0.f, 0.f, 0.f};

    #pragma unroll
    for (int kt = 0; kt < 8; ++kt) {
        short8v b_[8];
        #pragma unroll
        for (int n = 0; n < 8; ++n)
            b_[n] = *(const short8v*)&B1op[(size_t)(w * 128 + n * 16 + lr_) * 256 + kt * 32 + lk * 8];
        int T = kt >> 1;
        int q2 = (((kt & 1) * 4 + lk) ^ r7) ^ (((kt >> 2) & 1) << 2);
        short8v a_[4];
        #pragma unroll
        for (int m = 0; m < 4; ++m)
            a_[m] = *(const short8v*)(As + T * 8192 + (m * 16 + lr_) * 128 + (q2 << 4));
        #pragma unroll
        for (int n = 0; n < 8; ++n)
            #pragma unroll
            for (int m = 0; m < 4; ++m)
                acc[m][n] = __builtin_amdgcn_mfma_f32_16x16x32_bf16(a_[m], b_[n], acc[m][n], 0, 0, 0);
    }

    // epilogue: pair re/im via shfl, write BuT, in-register chunk-final scan
    size_t cb = (size_t)ci * 16384;            // 64*256 dwords per chunk
    bool evenl = (lr_ & 1) == 0;
    int mA = evenl ? 0 : 2;
    #pragma unroll
    for (int n = 0; n < 8; ++n) {
        int p = w * 64 + n * 8 + (lr_ >> 1);
        unsigned dw[4][4];
        #pragma unroll
        for (int m = 0; m < 4; ++m)
            #pragma unroll
            for (int i = 0; i < 4; ++i) {
                float mv = acc[m][n][i];
                float pv = __shfl_xor(mv, 1);
                dw[m][i] = evenl ? pack_bf16x2(mv, pv) : pack_bf16x2(pv, mv);
            }
        #pragma unroll
        for (int t2 = 0; t2 < 2; ++t2) {
            int m = mA + t2;
            uint4 vv = make_uint4(dw[m][0], dw[m][1], dw[m][2], dw[m][3]);
            *(uint4*)&BuT[cb + (size_t)p * 64 + m * 16 + lk * 4] = vv;
        }
        // scan from bf16-rounded values (consistent with g2f's re-scan)
        const float4* lp = (const float4*)(lamP + 16 * p);
        float4 P0 = lp[0], P1 = lp[1], P2 = lp[2], P3 = lp[3];
        float Lr = P0.x, Li = P0.y;
        float Fr[4], Fi[4];
        #pragma unroll
        for (int m = 0; m < 4; ++m) {
            float fr = 0.f, fi = 0.f;
            #pragma unroll
            for (int i = 0; i < 4; ++i) {
                float ur = __uint_as_float(dw[m][i] << 16);
                float ui = __uint_as_float(dw[m][i] & 0xffff0000u);
                float nr2 = Lr * fr - Li * fi + ur;
                float ni2 = Lr * fi + Li * fr + ui;
                fr = nr2; fi = ni2;
            }
            Fr[m] = fr; Fi[m] = fi;
        }
        // H = l48*F0 + l32*F1 + l16*F2 + F3
        float Hr = Fr[3] + P3.x*Fr[0] - P3.y*Fi[0] + P2.z*Fr[1] - P2.w*Fi[1] + P2.x*Fr[2] - P2.y*Fi[2];
        float Hi = Fi[3] + P3.x*Fi[0] + P3.y*Fr[0] + P2.z*Fi[1] + P2.w*Fr[1] + P2.x*Fi[2] + P2.y*Fr[2];
        // G = l^{4*(3-lk)} * H
        float gr = (lk == 3) ? 1.f : (lk == 2) ? P0.z : (lk == 1) ? P1.x : P1.z;
        float gi = (lk == 3) ? 0.f : (lk == 2) ? P0.w : (lk == 1) ? P1.y : P1.w;
        float Gr = gr * Hr - gi * Hi;
        float Gi = gr * Hi + gi * Hr;
        float t1r = __shfl_xor(Gr, 16), t1i = __shfl_xor(Gi, 16);
        Gr += t1r; Gi += t1i;
        float t2r = __shfl_xor(Gr, 32), t2i = __shfl_xor(Gi, 32);
        Gr += t2r; Gi += t2i;
        if (evenl && lk == 0)
            sfin[(size_t)ci * P_ + p] = make_float2(Gr, Gi);
    }
}

// ---------------- s2: cross-chunk chain (grid = nb blocks) -----------------
__global__ __launch_bounds__(256) void s2_chain(
    const float* __restrict__ lamLc, const float2* __restrict__ sfin,
    float2* __restrict__ sinv)
{
    int bl = blockIdx.x;
    int p = threadIdx.x;
    float ar = lamLc[2 * p], ai = lamLc[2 * p + 1];
    float sr = 0.f, si = 0.f;
    #pragma unroll 8
    for (int c = 0; c < NC; ++c) {
        sinv[(size_t)(bl * NC + c) * P_ + p] = make_float2(sr, si);
        float2 f = sfin[(size_t)(bl * NC + c) * P_ + p];
        float nr = ar * sr - ai * si + f.x;
        float ni = ar * si + ai * sr + f.y;
        sr = nr; si = ni;
    }
}

// ---------------- g2f: per-chunk scan + full-H output GEMM + D*u -----------
// block = 1 chunk (64 rows) x H=256; BuT read contiguous per lane.
__global__ __launch_bounds__(256) void g2f_gemm(
    const unsigned* __restrict__ BuT,
    const unsigned short* __restrict__ C2op,
    const float* __restrict__ lam, const float2* __restrict__ sinv,
    const float* __restrict__ useg, const float* __restrict__ Dv,
    float* __restrict__ yseg)
{
    __shared__ __align__(16) char xs[64 * 1024];
    int tid = threadIdx.x, w = tid >> 6, lane = tid & 63;
    int ci = blockIdx.x;

    // phase 1: scan this chunk, write x (bf16) to swizzled LDS
    {
        int p = tid;
        float lr = lam[2 * p], li = lam[2 * p + 1];
        float2 s0 = sinv[(size_t)ci * P_ + p];
        const uint4* bp = (const uint4*)(BuT + (size_t)ci * 16384 + (size_t)p * 64);
        uint4 dq[16];
        #pragma unroll
        for (int t = 0; t < 16; ++t) dq[t] = bp[t];
        float xr = s0.x, xi = s0.y;
        int T = p >> 5, qd = (p & 31) >> 2, pos = p & 3;
        char* base = xs + T * 8192 + (pos << 2);
        #pragma unroll
        for (int t = 0; t < 16; ++t) {
            unsigned wv4[4] = {dq[t].x, dq[t].y, dq[t].z, dq[t].w};
            #pragma unroll
            for (int e = 0; e < 4; ++e) {
                int j = t * 4 + e;
                unsigned wv = wv4[e];
                float ur = __uint_as_float(wv << 16);
                float ui = __uint_as_float(wv & 0xffff0000u);
                float nr = lr * xr - li * xi + ur;
                float ni = lr * xi + li * xr + ui;
                xr = nr; xi = ni;
                *(unsigned*)(base + j * 128 + ((qd ^ (j & 7)) << 4)) = pack_bf16x2(xr, xi);
            }
        }
    }
    __syncthreads();

    // phase 2: GEMM  y[64][256] = x[64][512] * C2op^T[512][256]
    int lr_ = lane & 15, lk = lane >> 4;
    int r7 = lr_ & 7;
    int h0 = w * 64;
    f32x4 acc[4][4];
    #pragma unroll
    for (int m = 0; m < 4; ++m)
        #pragma unroll
        for (int n = 0; n < 4; ++n)
            acc[m][n] = (f32x4){0.f, 0.f, 0.f, 0.f};

    for (int kt = 0; kt < 16; ++kt) {
        int T = kt >> 1, q2 = (kt & 1) * 4 + lk;
        short8v a_[4], b_[4];
        #pragma unroll
        for (int m = 0; m < 4; ++m) {
            int row = m * 16 + lr_;
            a_[m] = *(const short8v*)(xs + T * 8192 + row * 128 + ((q2 ^ r7) << 4));
        }
        #pragma unroll
        for (int n = 0; n < 4; ++n)
            b_[n] = *(const short8v*)&C2op[(size_t)(h0 + n * 16 + lr_) * 512 + kt * 32 + lk * 8];
        #pragma unroll
        for (int m = 0; m < 4; ++m)
            #pragma unroll
            for (int n = 0; n < 4; ++n)
                acc[m][n] = __builtin_amdgcn_mfma_f32_16x16x32_bf16(a_[m], b_[n], acc[m][n], 0, 0, 0);
    }

    float d_[4];
    #pragma unroll
    for (int n = 0; n < 4; ++n) d_[n] = Dv[h0 + n * 16 + lr_];
    #pragma unroll
    for (int m = 0; m < 4; ++m)
        #pragma unroll
        for (int n = 0; n < 4; ++n)
            #pragma unroll
            for (int i = 0; i < 4; ++i) {
                int rl = m * 16 + lk * 4 + i;
                int col = h0 + n * 16 + lr_;
                size_t off = ((size_t)ci * 64 + rl) * 256 + col;
                yseg[off] = acc[m][n][i] + d_[n] * useg[off];
            }
}

// ---------------- launch ----------------
extern "C" void kernel_launch(void* const* d_in, const int* in_sizes, int n_in,
                              void* d_out, int out_size, void* d_ws, size_t ws_size,
                              hipStream_t stream) {
    (void)in_sizes; (void)n_in; (void)out_size;
    const float* u    = (const float*)d_in[0];
    const float* Lre  = (const float*)d_in[1];
    const float* Lim  = (const float*)d_in[2];
    const float* Bre  = (const float*)d_in[3];
    const float* Bim  = (const float*)d_in[4];
    const float* Cre  = (const float*)d_in[5];
    const float* Cim  = (const float*)d_in[6];
    const float* Dv   = (const float*)d_in[7];
    const float* lstep= (const float*)d_in[8];

    // pick largest segment size the workspace allows
    const size_t fixed = 2048 + 2048 + (size_t)16 * P_ * 4
                       + (size_t)512 * 256 * 2 + (size_t)256 * 512 * 2;
    int nb = 4;
    {
        size_t per16 = (size_t)16 * (NC * P_ * 8 * 2 + (size_t)L_ * 256 * 4);
        size_t per8  = per16 / 2;
        if (ws_size >= fixed + per16 + 4096) nb = 16;
        else if (ws_size >= fixed + per8 + 4096) nb = 8;
    }
    int nseg = B_ / nb;

    char* w0 = (char*)d_ws;
    float* lam   = (float*)w0;  w0 += 2048;
    float* lamLc = (float*)w0;  w0 += 2048;
    float* lamP  = (float*)w0;  w0 += (size_t)16 * P_ * 4;
    unsigned short* B1op = (unsigned short*)w0; w0 += (size_t)512 * 256 * 2;
    unsigned short* C2op = (unsigned short*)w0; w0 += (size_t)256 * 512 * 2;
    float2* sfin = (float2*)w0; w0 += (size_t)nb * NC * P_ * 8;
    float2* sinv = (float2*)w0; w0 += (size_t)nb * NC * P_ * 8;
    unsigned* BuT = (unsigned*)w0;

    k0_pre<<<256, 256, 0, stream>>>(Lre, Lim, Bre, Bim, Cre, Cim, lstep,
                                    lam, lamLc, lamP, B1op, C2op);
    for (int s = 0; s < nseg; ++s) {
        const float* us = u + (size_t)s * nb * L_ * H_;
        float* ys = (float*)d_out + (size_t)s * nb * L_ * H_;
        g1c_gemm<<<nb * NC, 256, 0, stream>>>(us, B1op, lamP, BuT, sfin);
        s2_chain<<<nb, 256, 0, stream>>>(lamLc, sfin, sinv);
        g2f_gemm<<<nb * NC, 256, 0, stream>>>(BuT, C2op, lam, sinv, us, Dv, ys);
    }
}